// Round 10
// baseline (180.203 us; speedup 1.0000x reference)
//
#include <hip/hip_runtime.h>

#define N_HITS 4000000
#define N_QUADS (N_HITS / 4)
#define N_OCTS  (N_HITS / 8)
#define N_SHOWERS 10000
#define NUM_SEGMENTS (N_SHOWERS + 1)
#define ACC_STRIDE 20004                   // 2*NUM_SEGMENTS padded to %4==0
#define ACC_STRIDE4 (ACC_STRIDE / 4)       // 5001 float4 columns
#define R_BLOCKS 512                       // scatter blocks == replica count
#define G_PART 16                          // first-level reduction fan-in

typedef float f4 __attribute__((ext_vector_type(4)));  // clang vector: works
                                                       // with nontemporal_store

// ---------------------------------------------------------------------------
// Scratch layout (only 160 KB of d_ws assumed, proven since round 1):
//   d_ws [0, 160016)              : float4 vals[NUM_SEGMENTS]
//   d_out float-offset 0          : float acc [R_BLOCKS][ACC_STRIDE]  (41 MB)
//   d_out float-offset ACC2_OFF   : float acc2[G_PART ][ACC_STRIDE]  (1.3 MB)
// d_out (16M floats, 64 MB) is free scratch until gather overwrites all of it;
// acc/acc2 are fully consumed by reduce/corr BEFORE gather (stream-ordered).
// Replica layout: [hit: 0..10000][track: 10001..20001][pad: 2 zeros]
// ---------------------------------------------------------------------------
#define ACC2_OFF ((size_t)R_BLOCKS * ACC_STRIDE)

__global__ __launch_bounds__(1024) void
scatter_kernel(const int4* __restrict__ sid4,
               const float4* __restrict__ e4,
               const int4* __restrict__ rid4,
               f4* __restrict__ acc4) {
    __shared__ float h[ACC_STRIDE];                  // 80,016 B -> 2 blocks/CU
    f4* h4 = (f4*)h;
    for (int i = threadIdx.x; i < ACC_STRIDE4; i += 1024)
        h4[i] = (f4){0.f, 0.f, 0.f, 0.f};
    __syncthreads();
    int t = blockIdx.x * 1024 + threadIdx.x;         // oct index, single pass
    if (t < N_OCTS) {
        #pragma unroll
        for (int q = 0; q < 2; ++q) {                // two quads = 8 hits
            int4   s = sid4[2 * t + q];
            float4 e = e4[2 * t + q];
            int4   r = rid4[2 * t + q];
            // rid==0 -> hit half [0,10001), rid==1 -> track half [10001,20002)
            if (s.x >= 0) atomicAdd(&h[r.x * NUM_SEGMENTS + s.x + 1], e.x);
            if (s.y >= 0) atomicAdd(&h[r.y * NUM_SEGMENTS + s.y + 1], e.y);
            if (s.z >= 0) atomicAdd(&h[r.z * NUM_SEGMENTS + s.z + 1], e.z);
            if (s.w >= 0) atomicAdd(&h[r.w * NUM_SEGMENTS + s.w + 1], e.w);
        }
    }
    __syncthreads();
    f4* __restrict__ dst = acc4 + (size_t)blockIdx.x * ACC_STRIDE4;
    for (int i = threadIdx.x; i < ACC_STRIDE4; i += 1024)
        __builtin_nontemporal_store(h4[i], &dst[i]); // coalesced 16B flush
}

__global__ void reduce_kernel(const f4* __restrict__ acc4,
                              f4* __restrict__ acc2_4) {
    int c = blockIdx.x * 256 + threadIdx.x;          // float4 column 0..5000
    if (c >= ACC_STRIDE4) return;
    int g = blockIdx.y;                              // partial group 0..15
    f4 v = (f4){0.f, 0.f, 0.f, 0.f};
    for (int r = g; r < R_BLOCKS; r += G_PART)       // 32 coalesced 16B loads
        v += acc4[(size_t)r * ACC_STRIDE4 + c];
    __builtin_nontemporal_store(v, &acc2_4[(size_t)g * ACC_STRIDE4 + c]);
}

__global__ void corr_kernel(const int* __restrict__ sid,
                            const float* __restrict__ pcf,
                            const int* __restrict__ a_tracks,
                            const int* __restrict__ a_hits,
                            const float* __restrict__ acc2,
                            float4* __restrict__ vals) {
    int s = blockIdx.x * 256 + threadIdx.x;          // segment 0..10000
    if (s >= NUM_SEGMENTS) return;
    float eh = 0.0f, et = 0.0f;
    for (int g = 0; g < G_PART; ++g) {
        eh += acc2[(size_t)g * ACC_STRIDE + s];
        et += acc2[(size_t)g * ACC_STRIDE + NUM_SEGMENTS + s];
    }
    float ch = 0.0f, ct = 0.0f;
    if (s > 0) {
        int ih = a_hits[s - 1];                      // in [0, N_HITS]
        if (ih < N_HITS && sid[ih] != -1) ch = pcf[ih];
        int it = a_tracks[s - 1];
        if (it < N_HITS && sid[it] != -1) ct = pcf[it];
    }
    vals[s] = make_float4(et, et * ct, eh, eh * ch);
}

__global__ void gather_kernel(const int4* __restrict__ sid4,
                              const float4* __restrict__ vals,
                              f4* __restrict__ out) {
    int t = blockIdx.x * 256 + threadIdx.x;
    if (t >= N_QUADS) return;
    int4 s = sid4[t];
    float4 a = vals[s.x + 1];
    float4 b = vals[s.y + 1];
    float4 c = vals[s.z + 1];
    float4 d = vals[s.w + 1];
    __builtin_nontemporal_store((f4){a.x, b.x, c.x, d.x}, &out[t]);
    __builtin_nontemporal_store((f4){a.y, b.y, c.y, d.y}, &out[N_QUADS + t]);
    __builtin_nontemporal_store((f4){a.z, b.z, c.z, d.z}, &out[2 * N_QUADS + t]);
    __builtin_nontemporal_store((f4){a.w, b.w, c.w, d.w}, &out[3 * N_QUADS + t]);
}

extern "C" void kernel_launch(void* const* d_in, const int* in_sizes, int n_in,
                              void* d_out, int out_size, void* d_ws, size_t ws_size,
                              hipStream_t stream) {
    const int*   pred_sid = (const int*)  d_in[0];
    const float* pcf      = (const float*)d_in[1];
    const float* energy   = (const float*)d_in[2];
    const int*   rid      = (const int*)  d_in[3];
    // d_in[4] = pred_beta (unused)
    const int*   a_tracks = (const int*)  d_in[5];
    const int*   a_hits   = (const int*)  d_in[6];

    float*  out_f = (float*)d_out;
    float*  acc   = out_f;                  // [R_BLOCKS][ACC_STRIDE] scratch
    float*  acc2  = out_f + ACC2_OFF;       // [G_PART][ACC_STRIDE] scratch
    float4* vals  = (float4*)d_ws;          // 160 KB, survives into gather

    // 1) LDS-privatized segment-sum -> 512 replicas (no global atomics)
    scatter_kernel<<<R_BLOCKS, 1024, 0, stream>>>(
        (const int4*)pred_sid, (const float4*)energy, (const int4*)rid,
        (f4*)acc);
    // 2) replica tree-reduce 512 -> 16 (float4 columns)
    {
        dim3 grid((ACC_STRIDE4 + 255) / 256, G_PART);
        reduce_kernel<<<grid, 256, 0, stream>>>((const f4*)acc, (f4*)acc2);
    }
    // 3) 16 -> 1 + per-shower correction + packing
    corr_kernel<<<(NUM_SEGMENTS + 255) / 256, 256, 0, stream>>>(
        pred_sid, pcf, a_tracks, a_hits, acc2, vals);
    // 4) gather into the 4 output streams (overwrites ALL of d_out)
    gather_kernel<<<(N_QUADS + 255) / 256, 256, 0, stream>>>(
        (const int4*)pred_sid, vals, (f4*)d_out);
}

// Round 14
// 165.360 us; speedup vs baseline: 1.0898x; 1.0898x over previous
//
#include <hip/hip_runtime.h>

#define N_HITS 4000000
#define N_QUADS (N_HITS / 4)
#define N_SHOWERS 10000
#define NUM_SEGMENTS (N_SHOWERS + 1)
#define ACC_STRIDE 20004                   // 2*NUM_SEGMENTS padded to %4==0
#define ACC_STRIDE4 (ACC_STRIDE / 4)       // 5001 float4 columns
#define R_BLOCKS 256                       // scatter blocks == replica count (1/CU)
#define G_PART 16                          // first-level reduction fan-in
#define SC_THREADS (R_BLOCKS * 1024)       // 262144 scatter threads

typedef float f4 __attribute__((ext_vector_type(4)));

// ---------------------------------------------------------------------------
// Scratch layout (only 160 KB of d_ws assumed, proven since round 1):
//   d_ws [0, 160016)              : float4 vals[NUM_SEGMENTS]
//   d_out float-offset 0          : float acc [R_BLOCKS][ACC_STRIDE] (20.5 MB)
//   d_out float-offset ACC2_OFF   : float acc2[G_PART ][ACC_STRIDE] (1.3 MB)
// d_out (16M floats) is free scratch until gather overwrites all of it;
// acc/acc2 fully consumed by reduce/corr BEFORE gather (stream-ordered).
// Replica layout: [hit: 0..10000][track: 10001..20001][pad: 2 zeros]
// acc flush is PLAIN stores (re-read by reduce -> keep L2/L3 resident);
// only gather's final out stores are nontemporal (never re-read in-loop).
// ---------------------------------------------------------------------------
#define ACC2_OFF ((size_t)R_BLOCKS * ACC_STRIDE)

__global__ __launch_bounds__(1024) void
scatter_kernel(const int4* __restrict__ sid4,
               const float4* __restrict__ e4,
               const int4* __restrict__ rid4,
               f4* __restrict__ acc4) {
    __shared__ float h[ACC_STRIDE];                  // 80,016 B -> 1 block/CU
    f4* h4 = (f4*)h;
    for (int i = threadIdx.x; i < ACC_STRIDE4; i += 1024)
        h4[i] = (f4){0.f, 0.f, 0.f, 0.f};
    __syncthreads();
    int tid = blockIdx.x * 1024 + threadIdx.x;
    #pragma unroll
    for (int it = 0; it < 4; ++it) {                 // coalesced grid-stride
        int q = it * SC_THREADS + tid;               // quad index
        if (q < N_QUADS) {
            int4   s = sid4[q];
            float4 e = e4[q];
            int4   r = rid4[q];
            // rid==0 -> hit half [0,10001), rid==1 -> track half [10001,20002)
            if (s.x >= 0) atomicAdd(&h[r.x * NUM_SEGMENTS + s.x + 1], e.x);
            if (s.y >= 0) atomicAdd(&h[r.y * NUM_SEGMENTS + s.y + 1], e.y);
            if (s.z >= 0) atomicAdd(&h[r.z * NUM_SEGMENTS + s.z + 1], e.z);
            if (s.w >= 0) atomicAdd(&h[r.w * NUM_SEGMENTS + s.w + 1], e.w);
        }
    }
    __syncthreads();
    f4* __restrict__ dst = acc4 + (size_t)blockIdx.x * ACC_STRIDE4;
    for (int i = threadIdx.x; i < ACC_STRIDE4; i += 1024)
        dst[i] = h4[i];                              // plain store: stay cached
}

__global__ void reduce_kernel(const f4* __restrict__ acc4,
                              f4* __restrict__ acc2_4) {
    int c = blockIdx.x * 256 + threadIdx.x;          // float4 column 0..5000
    if (c >= ACC_STRIDE4) return;
    int g = blockIdx.y;                              // partial group 0..15
    f4 v = (f4){0.f, 0.f, 0.f, 0.f};
    for (int r = g; r < R_BLOCKS; r += G_PART)       // 16 coalesced 16B loads
        v += acc4[(size_t)r * ACC_STRIDE4 + c];
    acc2_4[(size_t)g * ACC_STRIDE4 + c] = v;
}

__global__ void corr_kernel(const int* __restrict__ sid,
                            const float* __restrict__ pcf,
                            const int* __restrict__ a_tracks,
                            const int* __restrict__ a_hits,
                            const float* __restrict__ acc2,
                            float4* __restrict__ vals) {
    int s = blockIdx.x * 256 + threadIdx.x;          // segment 0..10000
    if (s >= NUM_SEGMENTS) return;
    float eh = 0.0f, et = 0.0f;
    for (int g = 0; g < G_PART; ++g) {
        eh += acc2[(size_t)g * ACC_STRIDE + s];
        et += acc2[(size_t)g * ACC_STRIDE + NUM_SEGMENTS + s];
    }
    float ch = 0.0f, ct = 0.0f;
    if (s > 0) {
        int ih = a_hits[s - 1];                      // in [0, N_HITS]
        if (ih < N_HITS && sid[ih] != -1) ch = pcf[ih];
        int it = a_tracks[s - 1];
        if (it < N_HITS && sid[it] != -1) ct = pcf[it];
    }
    vals[s] = make_float4(et, et * ct, eh, eh * ch);
}

__global__ void gather_kernel(const int4* __restrict__ sid4,
                              const float4* __restrict__ vals,
                              f4* __restrict__ out) {
    int t = blockIdx.x * 256 + threadIdx.x;
    if (t >= N_QUADS) return;
    int4 s = sid4[t];
    float4 a = vals[s.x + 1];
    float4 b = vals[s.y + 1];
    float4 c = vals[s.z + 1];
    float4 d = vals[s.w + 1];
    __builtin_nontemporal_store((f4){a.x, b.x, c.x, d.x}, &out[t]);
    __builtin_nontemporal_store((f4){a.y, b.y, c.y, d.y}, &out[N_QUADS + t]);
    __builtin_nontemporal_store((f4){a.z, b.z, c.z, d.z}, &out[2 * N_QUADS + t]);
    __builtin_nontemporal_store((f4){a.w, b.w, c.w, d.w}, &out[3 * N_QUADS + t]);
}

extern "C" void kernel_launch(void* const* d_in, const int* in_sizes, int n_in,
                              void* d_out, int out_size, void* d_ws, size_t ws_size,
                              hipStream_t stream) {
    const int*   pred_sid = (const int*)  d_in[0];
    const float* pcf      = (const float*)d_in[1];
    const float* energy   = (const float*)d_in[2];
    const int*   rid      = (const int*)  d_in[3];
    // d_in[4] = pred_beta (unused)
    const int*   a_tracks = (const int*)  d_in[5];
    const int*   a_hits   = (const int*)  d_in[6];

    float*  out_f = (float*)d_out;
    float*  acc   = out_f;                  // [R_BLOCKS][ACC_STRIDE] scratch
    float*  acc2  = out_f + ACC2_OFF;       // [G_PART][ACC_STRIDE] scratch
    float4* vals  = (float4*)d_ws;          // 160 KB, survives into gather

    // 1) LDS-privatized segment-sum -> 256 replicas (no global atomics)
    scatter_kernel<<<R_BLOCKS, 1024, 0, stream>>>(
        (const int4*)pred_sid, (const float4*)energy, (const int4*)rid,
        (f4*)acc);
    // 2) replica tree-reduce 256 -> 16 (float4 columns)
    {
        dim3 grid((ACC_STRIDE4 + 255) / 256, G_PART);
        reduce_kernel<<<grid, 256, 0, stream>>>((const f4*)acc, (f4*)acc2);
    }
    // 3) 16 -> 1 + per-shower correction + packing
    corr_kernel<<<(NUM_SEGMENTS + 255) / 256, 256, 0, stream>>>(
        pred_sid, pcf, a_tracks, a_hits, acc2, vals);
    // 4) gather into the 4 output streams (overwrites ALL of d_out)
    gather_kernel<<<(N_QUADS + 255) / 256, 256, 0, stream>>>(
        (const int4*)pred_sid, vals, (f4*)d_out);
}